// Round 12
// baseline (65.554 us; speedup 1.0000x reference)
//
#include <hip/hip_runtime.h>
#include <hip/hip_fp16.h>

#define N 224        // image size
#define M 32         // CUT (number of sine modes)
#define NPIX (N * N) // 50176
#define NPLANE 384   // 128 * 3
#define PLT 128      // planes per remap group
#define NPGRP 3      // 384 / 128
#define NXT 784      // transpose pixel tiles (50176/64)
#define TTILE (NXT * NPGRP)   // 2352 transpose blocks
#define RPX 64       // remap pixel tile
#define NCHUNK (NPIX / RPX)   // 784
#define NXCD 8
#define CPX (NCHUNK / NXCD)   // 98
#define PI_F 3.14159265358979323846f

typedef float vfloat4 __attribute__((ext_vector_type(4)));
typedef float vfloat2 __attribute__((ext_vector_type(2)));

// --- Fused stage 1+2. Blocks [0, 2352): transpose tiles (128 planes x 64 px).
// Blocks [2352, 2576): field rows (placed LAST -> they fill the grid's drain
// phase instead of delaying the streaming start).
//
// Transpose tile: LDS f32 [128][65] (odd stride: row p contributes p mod 32
// to the bank index).
//   load : float4/lane, 4 plane-rows/inst (4 x 256 B segments); banks
//          (p + 4c + j) with q+4c covering 0..63 -> 2-way, free.
//   store: uint4/lane = 8 fp16 planes, 4 pixel-rows/inst (4 x 256 B
//          contiguous segments). Wide stores made conflict-free by a plane
//          SLOT PERMUTATION in xt: slot 8c+k <-> plane 4c+(k&3)+64*(k>>2),
//          so lane reads LDS rows {4c..4c+3, 4c+64..4c+67}: bank =
//          (4c+k+P) -> 2-way, free. Remap decodes the permutation when
//          scattering into its own LDS tile (it re-transposes anyway).
// xt layout: [pix][384] fp16, slot-permuted within each 128-plane group.
__global__ __launch_bounds__(256) void fused_field_transpose(
    const float* __restrict__ x, const float* __restrict__ Fx,
    const float* __restrict__ Fy, int4* __restrict__ tab,
    __half* __restrict__ xt)
{
    __shared__ float pool[128 * 65];   // 33,280 B, shared by both branches
    const int tid = threadIdx.x;

    if (blockIdx.x >= TTILE) {
        // ---------------- field body (one block per row y) ----------------
        float (*cx)[M] = (float(*)[M])pool;
        float (*cy)[M] = (float(*)[M])(pool + M * M);
        float *sy = pool + 2 * M * M;

        const int y = blockIdx.x - TTILE;

        for (int idx = tid; idx < M * M; idx += 256) {
            const int i = idx / M, j = idx % M;
            const float fi = (float)(i + 1), fj = (float)(j + 1);
            const float r = sqrtf(fi * fi + fj * fj);
            const float e = (r < (float)M + 0.5f) ? (1.0f / r) : 0.0f;
            cx[i][j] = Fx[idx] * e;
            cy[i][j] = Fy[idx] * e;
        }
        if (tid < M) {
            const float ys = (float)y / (float)(N - 1);
            sy[tid] = sinf(PI_F * ys * (float)(tid + 1));
        }
        __syncthreads();

        if (tid >= N) return;
        const int xi = tid;

        float sx[M];
        const float xsv = (float)xi / (float)(N - 1);
#pragma unroll
        for (int i = 0; i < M; ++i)
            sx[i] = sinf(PI_F * xsv * (float)(i + 1));

        float u = 0.0f, v = 0.0f;
#pragma unroll 1
        for (int j = 0; j < M; ++j) {
            float tx = 0.0f, ty = 0.0f;
#pragma unroll
            for (int i = 0; i < M; ++i) {
                tx = fmaf(cx[i][j], sx[i], tx);
                ty = fmaf(cy[i][j], sx[i], ty);
            }
            const float syj = sy[j];
            u = fmaf(syj, tx, u);
            v = fmaf(syj, ty, v);
        }

        const float dxv = 22.4f * u;   // sqrt(T)*n = 0.1*224
        const float dyv = 22.4f * v;
        const float xn = fminf(fmaxf((float)xi + dxv, 0.0f), (float)(N - 1));
        const float yn = fminf(fmaxf((float)y + dyv, 0.0f), (float)(N - 1));
        const int bx = min((int)floorf(xn), N - 2);
        const int by = min((int)floorf(yn), N - 2);
        const float fx = xn - (float)bx;
        const float fy = yn - (float)by;

        tab[y * N + xi] = make_int4(by * N + bx,
                                    __float_as_int(fx), __float_as_int(fy), 0);
        return;
    }

    // ---------------- transpose body ----------------
    float (*t)[65] = (float(*)[65])pool;

    const int tb    = blockIdx.x;      // 0..2351
    const int pg    = tb / NXT;        // 0..2 (plane group of 128)
    const int xtile = tb % NXT;        // 0..783 (consecutive blocks stream px)
    const int pl0   = pg * 128;
    const int pix0  = xtile * 64;

    const int c = tid & 15;            // 0..15
    const int q = (tid >> 4) & 3;      // 0..3
    const int w = tid >> 6;            // 0..3

    // load: plane-row p = 16*i + (tid>>4); 64 px as float4 per 16 lanes
#pragma unroll
    for (int i = 0; i < 8; ++i) {
        const int p = 16 * i + (tid >> 4);
        const vfloat4 v = *(const vfloat4*)(
            x + (size_t)(pl0 + p) * NPIX + pix0 + 4 * c);
        t[p][4 * c + 0] = v.x;
        t[p][4 * c + 1] = v.y;
        t[p][4 * c + 2] = v.z;
        t[p][4 * c + 3] = v.w;
    }
    __syncthreads();

    // store: pixel P = w*16 + s*4 + q; 8 slot-permuted planes per lane
    __half* xo = xt + (size_t)pix0 * NPLANE + pl0;
#pragma unroll
    for (int s = 0; s < 4; ++s) {
        const int P = w * 16 + s * 4 + q;
        union { uint4 u; __half2 hh[4]; } pk;
        pk.hh[0] = __floats2half2_rn(t[4 * c + 0][P],  t[4 * c + 1][P]);
        pk.hh[1] = __floats2half2_rn(t[4 * c + 2][P],  t[4 * c + 3][P]);
        pk.hh[2] = __floats2half2_rn(t[4 * c + 64][P], t[4 * c + 65][P]);
        pk.hh[3] = __floats2half2_rn(t[4 * c + 66][P], t[4 * c + 67][P]);
        *(uint4*)&xo[(size_t)P * NPLANE + 8 * c] = pk.u;
    }
}

// --- Stage 3: remap, planes-in-lanes (r8 structure; xt[pix][384] slot-
// permuted). Block = 64 pixels x 128 planes (one pgrp). Gather: per pixel,
// 4 coalesced half2 loads (lane = slot-pair, 256 B slice). Lane's slot-pair
// (2l,2l+1) decodes to actual plane pair (r0, r0+1) with
// r0 = 4*(l>>2) + 2*(l&1) + 64*((l&3)>>1). LDS tile re-transposes;
// stores vfloat2/lane nontemporal.
// Grid XCD-clustered: xcd owns pixel chunks [xcd*98,(xcd+1)*98) per pgrp.
__global__ __launch_bounds__(256) void remap_kernel(
    const __half* __restrict__ xt, const int4* __restrict__ tab,
    float* __restrict__ out)
{
    __shared__ float tile[RPX][130];
    __shared__ int4 ltab[RPX];

    const int tid = threadIdx.x;
    const int w = tid >> 6, l = tid & 63;

    const int bid   = blockIdx.x;
    const int xcd   = bid & 7;
    const int local = bid >> 3;          // 0..293
    const int pg    = local / CPX;       // 0..2
    const int chunk = xcd * CPX + (local % CPX);
    const int pix0  = chunk * RPX;

    if (tid < RPX) ltab[tid] = tab[pix0 + tid];
    __syncthreads();

    const __half2* base = (const __half2*)xt;
    const int pgoff = pg * (PLT / 2);    // half2 offset within a pixel row

    // decode slot-pair (2l,2l+1) -> actual plane pair (r0, r0+1)
    const int r0 = 4 * (l >> 2) + 2 * (l & 1) + 64 * ((l & 3) >> 1);

#pragma unroll 8
    for (int i = 0; i < 16; ++i) {
        const int pl = w * 16 + i;       // pixel-local index
        const int4 tb = ltab[pl];
        const float fx = __int_as_float(tb.y);
        const float fy = __int_as_float(tb.z);
        const float omx = 1.0f - fx, omy = 1.0f - fy;
        const float w00 = omy * omx, w01 = omy * fx;
        const float w10 = fy * omx,  w11 = fy * fx;

        const size_t b0 = (size_t)tb.x * (NPLANE / 2) + pgoff;
        const float2 c00 = __half22float2(base[b0 + l]);                          // (by,  bx)
        const float2 c01 = __half22float2(base[b0 + NPLANE / 2 + l]);             // (by,  bx+1)
        const float2 c10 = __half22float2(base[b0 + (size_t)N * (NPLANE/2) + l]); // (by+1,bx)
        const float2 c11 = __half22float2(base[b0 + (size_t)(N + 1) * (NPLANE/2) + l]); // (by+1,bx+1)

        float2 o;
        o.x = w00 * c00.x + w01 * c01.x + w10 * c10.x + w11 * c11.x;
        o.y = w00 * c00.y + w01 * c01.y + w10 * c10.y + w11 * c11.y;
        *(float2*)&tile[pl][r0] = o;     // planes (r0, r0+1) of pixel pl
    }
    __syncthreads();

    const int l2 = tid & 31, jg = tid >> 5;   // pixel-pair, plane-group
    float* ob = out + (size_t)pg * PLT * NPIX + pix0;
#pragma unroll
    for (int s = 0; s < 16; ++s) {
        const int j = jg * 16 + s;            // plane 0..127
        vfloat2 o2;
        o2.x = tile[2 * l2][j];
        o2.y = tile[2 * l2 + 1][j];
        __builtin_nontemporal_store(o2, (vfloat2*)&ob[(size_t)j * NPIX + 2 * l2]);
    }
}

extern "C" void kernel_launch(void* const* d_in, const int* in_sizes, int n_in,
                              void* d_out, int out_size, void* d_ws, size_t ws_size,
                              hipStream_t stream) {
    const float* x  = (const float*)d_in[0];   // [128,3,224,224]
    const float* Fx = (const float*)d_in[1];   // [32,32]
    const float* Fy = (const float*)d_in[2];   // [32,32]
    float* out = (float*)d_out;

    int4* tab = (int4*)d_ws;                               // 802,816 B
    const size_t tab_bytes = (size_t)NPIX * sizeof(int4);
    __half* xt = (__half*)((char*)d_ws + tab_bytes);       // [50176][384] fp16, 38.5 MB

    fused_field_transpose<<<TTILE + N, 256, 0, stream>>>(x, Fx, Fy, tab, xt);
    remap_kernel<<<NCHUNK * NPGRP, 256, 0, stream>>>(xt, tab, out);
}